// Round 10
// baseline (172.177 us; speedup 1.0000x reference)
//
#include <hip/hip_runtime.h>
#include <stdint.h>

// BERT lattice embedding: ragged segment mean-pool.
// hidden: [B,S,H] f32, word_ids: [B,S] i32 (non-decreasing per sample),
// out: [B,T,H] f32; out[b,t,:] = mean of hidden[b,s,:] over s with
// word_ids[b,s]==t (zeros if no piece maps to t).
//
// v11: deepen the read burst (the one lever with consistent measured gains:
// v9 nt+persistence -4us, v10 xcd-slab + 2-row burst -4us).
//  - 4-row bursts: 12 independent nontemporal loads (12 KB) in flight per
//    wave per issue, up from 6. Overshoot rows clamp to SS-1 (valid memory,
//    same sample); discarded rows warm the same-XCD L2 for neighbor waves.
//  - unchanged from v10: XCD-contiguous remap q=(p%8)*200+p/8 (1600=8x200),
//    4 words/wave one-shot, named accumulators + wave-uniform word advance,
//    nontemporal loads and stores.
// Kernel A (bounds precompute, verified since v7) unchanged.

#define BB 64
#define SS 512
#define HH 768
#define TT 400
#define LN (TT + 1)        // bounds per sample (incl. sentinel)
#define NF4 (HH / 4)       // 192 float4 per row
#define WPW 4              // words per wave
#define WPB 16             // words per block (4 waves)
#define CPS (TT / WPB)     // word-chunks per sample = 25
#define NBLK (BB * CPS)    // 1600 blocks
#define NXCD 8
#define BPX (NBLK / NXCD)  // 200 blocks per XCD slab

typedef float f4 __attribute__((ext_vector_type(4)));

// ---- Kernel A: per-sample lower bounds into workspace ----
__global__ __launch_bounds__(256) void bounds_kernel(
    const int* __restrict__ word_ids, int* __restrict__ L)
{
    const int b   = blockIdx.x;
    const int tid = threadIdx.x;

    __shared__ int s_w[SS];
    __shared__ int s_L[LN];

    const int2* r2 = reinterpret_cast<const int2*>(word_ids + b * SS);
    reinterpret_cast<int2*>(s_w)[tid] = r2[tid];          // 512 ints
    for (int t = tid; t < LN; t += 256) s_L[t] = SS;      // sentinel fill
    __syncthreads();

    // For each s: words t with w[s-1] < t <= w[s] have lower_bound(t) == s.
    // Ranges disjoint across s -> race-free LDS writes.
    for (int s = tid; s < SS; s += 256) {
        const int w  = s_w[s];
        const int wp = (s == 0) ? -1 : s_w[s - 1];
        for (int t = wp + 1; t <= w; ++t) s_L[t] = s;
    }
    __syncthreads();

    int* Lb = L + b * LN;
    for (int t = tid; t < LN; t += 256) Lb[t] = s_L[t];   // coalesced
}

// ---- Kernel B: XCD-slabbed streaming pool, 4-row bursts ----
__global__ __launch_bounds__(256) void bert_lattice_pool_kernel(
    const float* __restrict__ hidden,
    const int* __restrict__ L,
    float* __restrict__ out)
{
    const int p  = blockIdx.x;
    const int q  = (p % NXCD) * BPX + p / NXCD;   // xcd-contiguous remap
    const int b  = q / CPS;
    const int w0 = (q - b * CPS) * WPB + (threadIdx.x >> 6) * WPW;
    const int lane = threadIdx.x & 63;

    // Wave-uniform bounds for words w0..w0+3 (contiguous rows [b0, b4)).
    const int* Lb = L + b * LN + w0;
    const int b0 = Lb[0], b1 = Lb[1], b2 = Lb[2], b3 = Lb[3], b4 = Lb[4];

    const f4* hp = reinterpret_cast<const f4*>(hidden)
                   + (size_t)(b * SS) * NF4 + lane;

    const f4 z4 = {0.f, 0.f, 0.f, 0.f};
    f4 a00 = z4, a01 = z4, a02 = z4;   // word w0
    f4 a10 = z4, a11 = z4, a12 = z4;   // word w0+1
    f4 a20 = z4, a21 = z4, a22 = z4;   // word w0+2
    f4 a30 = z4, a31 = z4, a32 = z4;   // word w0+3

    int s = b0;
    const int send = b4;
    int t = 0;          // current word (wave-uniform, only increases)
    int e = b1;         // end row of current word

#define ADD_ROW(V0, V1, V2, SR)                                        \
    do {                                                               \
        while ((SR) >= e) { ++t; e = (t == 1) ? b2 : (t == 2) ? b3 : b4; } \
        switch (t) {                                                   \
            case 0: a00 += (V0); a01 += (V1); a02 += (V2); break;      \
            case 1: a10 += (V0); a11 += (V1); a12 += (V2); break;      \
            case 2: a20 += (V0); a21 += (V1); a22 += (V2); break;      \
            default: a30 += (V0); a31 += (V1); a32 += (V2); break;     \
        }                                                              \
    } while (0)

    while (s < send) {
        // Clamp to end of SAMPLE (valid memory); overshoot rows are real
        // neighbor rows -> discarded values but same-XCD L2 warm-up.
        const int s1c = (s + 1 < SS) ? s + 1 : SS - 1;
        const int s2c = (s + 2 < SS) ? s + 2 : SS - 1;
        const int s3c = (s + 3 < SS) ? s + 3 : SS - 1;
        const f4* p0 = hp + (size_t)s   * NF4;
        const f4* p1 = hp + (size_t)s1c * NF4;
        const f4* p2 = hp + (size_t)s2c * NF4;
        const f4* p3 = hp + (size_t)s3c * NF4;
        // 12 independent nontemporal loads in one basic block (12 KB/wave).
        const f4 u0 = __builtin_nontemporal_load(p0);
        const f4 u1 = __builtin_nontemporal_load(p0 + 64);
        const f4 u2 = __builtin_nontemporal_load(p0 + 128);
        const f4 v0 = __builtin_nontemporal_load(p1);
        const f4 v1 = __builtin_nontemporal_load(p1 + 64);
        const f4 v2 = __builtin_nontemporal_load(p1 + 128);
        const f4 w0v = __builtin_nontemporal_load(p2);
        const f4 w1v = __builtin_nontemporal_load(p2 + 64);
        const f4 w2v = __builtin_nontemporal_load(p2 + 128);
        const f4 x0 = __builtin_nontemporal_load(p3);
        const f4 x1 = __builtin_nontemporal_load(p3 + 64);
        const f4 x2 = __builtin_nontemporal_load(p3 + 128);

        ADD_ROW(u0, u1, u2, s);
        if (s + 1 < send) ADD_ROW(v0, v1, v2, s + 1);
        if (s + 2 < send) ADD_ROW(w0v, w1v, w2v, s + 2);
        if (s + 3 < send) ADD_ROW(x0, x1, x2, s + 3);
        s += 4;
    }
#undef ADD_ROW

    // Epilogue: means (empty words have zero acc; inv over max(cnt,1)).
    f4* o = reinterpret_cast<f4*>(out) + ((size_t)b * TT + w0) * NF4 + lane;
    {
        const int c = b1 - b0; const float inv = 1.0f / (float)(c > 0 ? c : 1);
        __builtin_nontemporal_store(a00 * inv, o);
        __builtin_nontemporal_store(a01 * inv, o + 64);
        __builtin_nontemporal_store(a02 * inv, o + 128);
    }
    o += NF4;
    {
        const int c = b2 - b1; const float inv = 1.0f / (float)(c > 0 ? c : 1);
        __builtin_nontemporal_store(a10 * inv, o);
        __builtin_nontemporal_store(a11 * inv, o + 64);
        __builtin_nontemporal_store(a12 * inv, o + 128);
    }
    o += NF4;
    {
        const int c = b3 - b2; const float inv = 1.0f / (float)(c > 0 ? c : 1);
        __builtin_nontemporal_store(a20 * inv, o);
        __builtin_nontemporal_store(a21 * inv, o + 64);
        __builtin_nontemporal_store(a22 * inv, o + 128);
    }
    o += NF4;
    {
        const int c = b4 - b3; const float inv = 1.0f / (float)(c > 0 ? c : 1);
        __builtin_nontemporal_store(a30 * inv, o);
        __builtin_nontemporal_store(a31 * inv, o + 64);
        __builtin_nontemporal_store(a32 * inv, o + 128);
    }
}

extern "C" void kernel_launch(void* const* d_in, const int* in_sizes, int n_in,
                              void* d_out, int out_size, void* d_ws, size_t ws_size,
                              hipStream_t stream) {
    (void)in_sizes; (void)n_in; (void)ws_size; (void)out_size;
    const float* hidden   = (const float*)d_in[0];
    const int*   word_ids = (const int*)d_in[1];
    float*       out      = (float*)d_out;
    int*         L        = (int*)d_ws;     // BB*LN ints = 102.7 KB

    bounds_kernel<<<dim3(BB), dim3(256), 0, stream>>>(word_ids, L);
    bert_lattice_pool_kernel<<<dim3(NBLK), dim3(256), 0, stream>>>(
        hidden, L, out);
}